// Round 1
// baseline (906.694 us; speedup 1.0000x reference)
//
#include <hip/hip_runtime.h>
#include <hip/hip_bf16.h>

// ---- problem constants (fixed by the reference) ----
#define N_BONDS 196608
#define HID     256
#define NSEG    4096
#define SMSCALE 0.17677669529663687f  // D^-0.5, D=32
#define LN_EPS  1e-5f
#define CHUNK   64                    // bonds per block in segment/elementwise kernels

typedef __hip_bfloat16 bf16;
typedef __attribute__((ext_vector_type(8))) short short8_t;  // 8 x bf16 (4 VGPR)
typedef __attribute__((ext_vector_type(4))) float f32x4_t;

__device__ __forceinline__ float bf2f(bf16 x) { return __bfloat162float(x); }

// 32-lane-group reductions inside a 64-lane wave (xor masks < 32 stay inside the head group)
__device__ __forceinline__ float gmax32(float x) {
#pragma unroll
    for (int m = 16; m >= 1; m >>= 1) x = fmaxf(x, __shfl_xor(x, m));
    return x;
}
__device__ __forceinline__ float gsum32(float x) {
#pragma unroll
    for (int m = 16; m >= 1; m >>= 1) x += __shfl_xor(x, m);
    return x;
}

// ---------------- f32 -> bf16 cast (x4 vectorized) ----------------
__global__ void cast_kernel(const float* __restrict__ src, ushort* __restrict__ dst, int n4) {
    int i = blockIdx.x * blockDim.x + threadIdx.x;
    const int stride = gridDim.x * blockDim.x;
    for (; i < n4; i += stride) {
        float4 v = reinterpret_cast<const float4*>(src)[i];
        union { ushort4 u; bf16 b[4]; } cv;
        cv.b[0] = __float2bfloat16(v.x);
        cv.b[1] = __float2bfloat16(v.y);
        cv.b[2] = __float2bfloat16(v.z);
        cv.b[3] = __float2bfloat16(v.w);
        reinterpret_cast<ushort4*>(dst)[i] = cv.u;
    }
}

// ---------------- GEMM: C[n,j] = sum_i A[n,i] * W[j,i]  (torch Linear, B^T form) ----------------
// A: [M,256] bf16, W: [256,256] bf16 row-major. grid.x = M/128 row tiles, grid.y = 2 col halves.
// Block: 256 threads = 4 waves; wave owns 32 rows x 128 cols (2x8 tiles of 16x16).
// W half (128 cols x 256 k, bf16 = 64 KB) staged in LDS with XOR swizzle:
//   byte(j,k) = j*512 + ((2k) ^ ((j&7)<<4))  -> 16 rows at same k-slice spread over 8 16B slots (2-way = free).
template <typename OutT>
__global__ __launch_bounds__(256, 2) void gemm_bt(const ushort* __restrict__ A,
                                                  const ushort* __restrict__ W,
                                                  OutT* __restrict__ C) {
    __shared__ __align__(16) char lds[128 * 512];
    const int t = threadIdx.x;
    const int colhalf = blockIdx.y;
    // stage W half: 128 rows x 32 chunks of 8 bf16
#pragma unroll
    for (int it = 0; it < 16; ++it) {
        int c = it * 256 + t;
        int j = c >> 5, kc = c & 31;
        uint4 val = *reinterpret_cast<const uint4*>(W + ((colhalf << 7) + j) * HID + (kc << 3));
        *reinterpret_cast<uint4*>(lds + j * 512 + ((kc << 4) ^ ((j & 7) << 4))) = val;
    }
    __syncthreads();

    const int wave = t >> 6, lane = t & 63;
    const int lr = lane & 15, lk = lane >> 4;  // tile row/col index, k-group
    const long rowbase = (long)blockIdx.x * 128 + wave * 32;

    f32x4_t acc[2][8];
#pragma unroll
    for (int r = 0; r < 2; ++r)
#pragma unroll
        for (int cc = 0; cc < 8; ++cc) acc[r][cc] = (f32x4_t){0.f, 0.f, 0.f, 0.f};

    const ushort* a0 = A + (rowbase + lr) * HID;
    const ushort* a1 = a0 + 16 * HID;
#pragma unroll
    for (int k0 = 0; k0 < HID; k0 += 32) {
        const int koff = k0 + lk * 8;
        short8_t af0 = *reinterpret_cast<const short8_t*>(a0 + koff);
        short8_t af1 = *reinterpret_cast<const short8_t*>(a1 + koff);
#pragma unroll
        for (int cc = 0; cc < 8; ++cc) {
            const int j = cc * 16 + lr;
            short8_t bfr = *reinterpret_cast<const short8_t*>(
                lds + j * 512 + (((k0 << 1) + (lk << 4)) ^ ((j & 7) << 4)));
            acc[0][cc] = __builtin_amdgcn_mfma_f32_16x16x32_bf16(af0, bfr, acc[0][cc], 0, 0, 0);
            acc[1][cc] = __builtin_amdgcn_mfma_f32_16x16x32_bf16(af1, bfr, acc[1][cc], 0, 0, 0);
        }
    }
    // C/D layout (verified m89): col = lane&15, row = (lane>>4)*4 + reg
#pragma unroll
    for (int r = 0; r < 2; ++r) {
#pragma unroll
        for (int cc = 0; cc < 8; ++cc) {
            const int col = (colhalf << 7) + cc * 16 + lr;
#pragma unroll
            for (int reg = 0; reg < 4; ++reg) {
                const long row = rowbase + r * 16 + lk * 4 + reg;
                const float v = acc[r][cc][reg];
                if constexpr (sizeof(OutT) == 2) C[row * HID + col] = __float2bfloat16(v);
                else                             C[row * HID + col] = v;
            }
        }
    }
}

// ---------------- alpha = softmax_d(q*w_alpha*scale); gq = segment_sum(alpha*q) ----------------
// Block: 256 threads (one per (h,d) element), CHUNK contiguous bonds. segment_ids sorted ->
// accumulate per segment in a register, atomicAdd only on segment change.
__global__ __launch_bounds__(256) void alpha_gq_kernel(const bf16* __restrict__ qb,
                                                       const float* __restrict__ w_alpha,
                                                       const int* __restrict__ seg,
                                                       float* __restrict__ gq) {
    const int j = threadIdx.x;
    const float wa = w_alpha[j & 31] * SMSCALE;
    const long n0 = (long)blockIdx.x * CHUNK;
    float acc = 0.f;
    int cur = -1;
    for (int i = 0; i < CHUNK; ++i) {
        const long n = n0 + i;
        const int s = seg[n];
        const float qv = bf2f(qb[n * HID + j]);
        const float x = qv * wa;
        const float m = gmax32(x);
        const float e = __expf(x - m);
        const float ssum = gsum32(e);
        const float alpha = e / ssum;
        if (s != cur) {
            if (cur >= 0) atomicAdd(&gq[(long)cur * HID + j], acc);
            acc = 0.f;
            cur = s;
        }
        acc += alpha * qv;
    }
    atomicAdd(&gq[(long)cur * HID + j], acc);
}

// ---------------- p = gq[seg]*k; beta = softmax_d(p*w_beta*scale); gk = segment_sum(beta*p) ----
__global__ __launch_bounds__(256) void beta_gk_kernel(const bf16* __restrict__ kb,
                                                      const float* __restrict__ gq,
                                                      const float* __restrict__ w_beta,
                                                      const int* __restrict__ seg,
                                                      float* __restrict__ gk) {
    const int j = threadIdx.x;
    const float wb = w_beta[j & 31] * SMSCALE;
    const long n0 = (long)blockIdx.x * CHUNK;
    float acc = 0.f;
    int cur = -1;
    for (int i = 0; i < CHUNK; ++i) {
        const long n = n0 + i;
        const int s = seg[n];
        const float kv = bf2f(kb[n * HID + j]);
        const float p = gq[(long)s * HID + j] * kv;
        const float x = p * wb;
        const float m = gmax32(x);
        const float e = __expf(x - m);
        const float ssum = gsum32(e);
        const float beta = e / ssum;
        if (s != cur) {
            if (cur >= 0) atomicAdd(&gk[(long)cur * HID + j], acc);
            acc = 0.f;
            cur = s;
        }
        acc += beta * p;
    }
    atomicAdd(&gk[(long)cur * HID + j], acc);
}

// ---------------- kvi = gk[seg]*v; act = relu(kvi @ W_r^T per head + q) (bf16 out) -----------
// Per-head D=32 dot done with __shfl: kvi[h,d] lives in lane (h&1)*32 + d of the same wave.
__global__ __launch_bounds__(256) void act_kernel(const bf16* __restrict__ vb,
                                                  const bf16* __restrict__ qb,
                                                  const float* __restrict__ gk,
                                                  const float* __restrict__ Wr,
                                                  const int* __restrict__ seg,
                                                  bf16* __restrict__ act) {
    const int j = threadIdx.x;
    const int e = j & 31;
    const int lane = j & 63;
    float wr[32];
#pragma unroll
    for (int d = 0; d < 32; ++d) wr[d] = Wr[e * 32 + d];  // row e of W_r
    const long n0 = (long)blockIdx.x * CHUNK;
    for (int i = 0; i < CHUNK; ++i) {
        const long n = n0 + i;
        const int s = seg[n];
        const float kvi = gk[(long)s * HID + j] * bf2f(vb[n * HID + j]);
        float dot = 0.f;
#pragma unroll
        for (int d = 0; d < 32; ++d) {
            const float kd = __shfl(kvi, (lane & 32) | d);
            dot = fmaf(kd, wr[d], dot);
        }
        const float qv = bf2f(qb[n * HID + j]);
        act[n * HID + j] = __float2bfloat16(fmaxf(dot + qv, 0.f));
    }
}

// ---------------- LayerNorm: one wave per row (4 f32 per lane), write d_out row n+1 ----------
__global__ __launch_bounds__(256) void ln_kernel(const float* __restrict__ tmp,
                                                 const float* __restrict__ b_o,
                                                 const float* __restrict__ gamma,
                                                 const float* __restrict__ beta_ln,
                                                 float* __restrict__ out) {
    const int wave = threadIdx.x >> 6, lane = threadIdx.x & 63;
    const long row = (long)blockIdx.x * 4 + wave;
    const float4 bo = reinterpret_cast<const float4*>(b_o)[lane];
    const float4 g = reinterpret_cast<const float4*>(gamma)[lane];
    const float4 bl = reinterpret_cast<const float4*>(beta_ln)[lane];
    float4 x = reinterpret_cast<const float4*>(tmp + row * HID)[lane];
    x.x += bo.x; x.y += bo.y; x.z += bo.z; x.w += bo.w;
    float s = x.x + x.y + x.z + x.w;
#pragma unroll
    for (int m = 32; m >= 1; m >>= 1) s += __shfl_xor(s, m);
    const float mu = s * (1.f / HID);
    float4 dx = {x.x - mu, x.y - mu, x.z - mu, x.w - mu};
    float sq = dx.x * dx.x + dx.y * dx.y + dx.z * dx.z + dx.w * dx.w;
#pragma unroll
    for (int m = 32; m >= 1; m >>= 1) sq += __shfl_xor(sq, m);
    const float r = rsqrtf(sq * (1.f / HID) + LN_EPS);
    float4 o;
    o.x = dx.x * r * g.x + bl.x;
    o.y = dx.y * r * g.y + bl.y;
    o.z = dx.z * r * g.z + bl.z;
    o.w = dx.w * r * g.w + bl.w;
    reinterpret_cast<float4*>(out + (row + 1) * HID)[lane] = o;
}

extern "C" void kernel_launch(void* const* d_in, const int* in_sizes, int n_in,
                              void* d_out, int out_size, void* d_ws, size_t ws_size,
                              hipStream_t stream) {
    const float* msg    = (const float*)d_in[0];
    const float* Wq     = (const float*)d_in[1];
    const float* Wk     = (const float*)d_in[2];
    const float* Wv     = (const float*)d_in[3];
    const float* Wr     = (const float*)d_in[4];
    const float* walpha = (const float*)d_in[5];
    const float* wbeta  = (const float*)d_in[6];
    const float* Wo     = (const float*)d_in[7];
    const float* bo     = (const float*)d_in[8];
    const float* gamma  = (const float*)d_in[9];
    const float* betaln = (const float*)d_in[10];
    const int*   seg    = (const int*)d_in[11];

    // workspace layout (~412 MB): msgb | qb | kb | vb | wqb wkb wvb wob | gq gk
    // act (bf16, N*H) reuses msgb (msg dead after QKV GEMMs);
    // tmp (f32, N*H)  reuses qb+kb (dead after act_kernel).
    char* ws = (char*)d_ws;
    const size_t nh = (size_t)N_BONDS * HID;
    size_t off = 0;
    bf16* msgb = (bf16*)(ws + off); off += nh * 2;
    bf16* qb   = (bf16*)(ws + off); off += nh * 2;
    bf16* kb   = (bf16*)(ws + off); off += nh * 2;
    bf16* vb   = (bf16*)(ws + off); off += nh * 2;
    bf16* wqb  = (bf16*)(ws + off); off += (size_t)HID * HID * 2;
    bf16* wkb  = (bf16*)(ws + off); off += (size_t)HID * HID * 2;
    bf16* wvb  = (bf16*)(ws + off); off += (size_t)HID * HID * 2;
    bf16* wob  = (bf16*)(ws + off); off += (size_t)HID * HID * 2;
    float* gq  = (float*)(ws + off); off += (size_t)NSEG * HID * 4;
    float* gk  = (float*)(ws + off); off += (size_t)NSEG * HID * 4;
    bf16*  act = msgb;
    float* tmp = (float*)qb;

    // zero the segment accumulators (gq|gk contiguous) and output row 0
    hipMemsetAsync(gq, 0, (size_t)2 * NSEG * HID * 4, stream);
    hipMemsetAsync(d_out, 0, HID * sizeof(float), stream);

    // casts
    cast_kernel<<<4096, 256, 0, stream>>>(msg, (ushort*)msgb, (int)(nh / 4));
    cast_kernel<<<64, 256, 0, stream>>>(Wq, (ushort*)wqb, HID * HID / 4);
    cast_kernel<<<64, 256, 0, stream>>>(Wk, (ushort*)wkb, HID * HID / 4);
    cast_kernel<<<64, 256, 0, stream>>>(Wv, (ushort*)wvb, HID * HID / 4);
    cast_kernel<<<64, 256, 0, stream>>>(Wo, (ushort*)wob, HID * HID / 4);

    // QKV projections
    dim3 gg(N_BONDS / 128, 2);
    gemm_bt<bf16><<<gg, 256, 0, stream>>>((const ushort*)msgb, (const ushort*)wqb, qb);
    gemm_bt<bf16><<<gg, 256, 0, stream>>>((const ushort*)msgb, (const ushort*)wkb, kb);
    gemm_bt<bf16><<<gg, 256, 0, stream>>>((const ushort*)msgb, (const ushort*)wvb, vb);

    // attention core
    alpha_gq_kernel<<<N_BONDS / CHUNK, 256, 0, stream>>>(qb, walpha, seg, gq);
    beta_gk_kernel<<<N_BONDS / CHUNK, 256, 0, stream>>>(kb, gq, wbeta, seg, gk);
    act_kernel<<<N_BONDS / CHUNK, 256, 0, stream>>>(vb, qb, gk, Wr, seg, act);

    // output projection + LayerNorm
    gemm_bt<float><<<gg, 256, 0, stream>>>((const ushort*)act, (const ushort*)wob, tmp);
    ln_kernel<<<N_BONDS / 4, 256, 0, stream>>>(tmp, bo, gamma, betaln, (float*)d_out);
}

// Round 6
// 716.020 us; speedup vs baseline: 1.2663x; 1.2663x over previous
//
#include <hip/hip_runtime.h>
#include <hip/hip_bf16.h>

// ---- problem constants (fixed by the reference) ----
#define N_BONDS 196608
#define HID     256
#define NSEG    4096
#define SMSCALE 0.17677669529663687f  // D^-0.5, D=32
#define LN_EPS  1e-5f
#define CHUNK   64                    // bonds per block in segment/elementwise kernels

typedef __hip_bfloat16 bf16;
typedef __attribute__((ext_vector_type(8))) short short8_t;  // 8 x bf16 (4 VGPR)
typedef __attribute__((ext_vector_type(4))) float f32x4_t;

__device__ __forceinline__ float bf2f(bf16 x) { return __bfloat162float(x); }
__device__ __forceinline__ short f2bs(float f) {
    union { bf16 b; short s; } cv; cv.b = __float2bfloat16(f); return cv.s;
}
__device__ __forceinline__ float us2f(ushort u) {
    union { ushort u; bf16 b; } cv; cv.u = u; return __bfloat162float(cv.b);
}

// 32-lane-group reductions inside a 64-lane wave (xor masks < 32 stay inside the head group)
__device__ __forceinline__ float gmax32(float x) {
#pragma unroll
    for (int m = 16; m >= 1; m >>= 1) x = fmaxf(x, __shfl_xor(x, m));
    return x;
}
__device__ __forceinline__ float gsum32(float x) {
#pragma unroll
    for (int m = 16; m >= 1; m >>= 1) x += __shfl_xor(x, m);
    return x;
}

// ---------------- f32 -> bf16 cast (x4 vectorized) ----------------
__global__ void cast_kernel(const float* __restrict__ src, ushort* __restrict__ dst, int n4) {
    int i = blockIdx.x * blockDim.x + threadIdx.x;
    const int stride = gridDim.x * blockDim.x;
    for (; i < n4; i += stride) {
        float4 v = reinterpret_cast<const float4*>(src)[i];
        union { ushort4 u; bf16 b[4]; } cv;
        cv.b[0] = __float2bfloat16(v.x);
        cv.b[1] = __float2bfloat16(v.y);
        cv.b[2] = __float2bfloat16(v.z);
        cv.b[3] = __float2bfloat16(v.w);
        reinterpret_cast<ushort4*>(dst)[i] = cv.u;
    }
}

// ---------------- GEMM: C[n,j] = sum_i A[n,i] * W[j,i]  (torch Linear, B^T form) ----------------
// VERBATIM from R1 (known-pass). grid.x = M/128 row tiles, grid.y = 2 col halves.
template <typename OutT>
__global__ __launch_bounds__(256, 2) void gemm_bt(const ushort* __restrict__ A,
                                                  const ushort* __restrict__ W,
                                                  OutT* __restrict__ C) {
    __shared__ __align__(16) char lds[128 * 512];
    const int t = threadIdx.x;
    const int colhalf = blockIdx.y;
#pragma unroll
    for (int it = 0; it < 16; ++it) {
        int c = it * 256 + t;
        int j = c >> 5, kc = c & 31;
        uint4 val = *reinterpret_cast<const uint4*>(W + ((colhalf << 7) + j) * HID + (kc << 3));
        *reinterpret_cast<uint4*>(lds + j * 512 + ((kc << 4) ^ ((j & 7) << 4))) = val;
    }
    __syncthreads();

    const int wave = t >> 6, lane = t & 63;
    const int lr = lane & 15, lk = lane >> 4;
    const long rowbase = (long)blockIdx.x * 128 + wave * 32;

    f32x4_t acc[2][8];
#pragma unroll
    for (int r = 0; r < 2; ++r)
#pragma unroll
        for (int cc = 0; cc < 8; ++cc) acc[r][cc] = (f32x4_t){0.f, 0.f, 0.f, 0.f};

    const ushort* a0 = A + (rowbase + lr) * HID;
    const ushort* a1 = a0 + 16 * HID;
#pragma unroll
    for (int k0 = 0; k0 < HID; k0 += 32) {
        const int koff = k0 + lk * 8;
        short8_t af0 = *reinterpret_cast<const short8_t*>(a0 + koff);
        short8_t af1 = *reinterpret_cast<const short8_t*>(a1 + koff);
#pragma unroll
        for (int cc = 0; cc < 8; ++cc) {
            const int j = cc * 16 + lr;
            short8_t bfr = *reinterpret_cast<const short8_t*>(
                lds + j * 512 + (((k0 << 1) + (lk << 4)) ^ ((j & 7) << 4)));
            acc[0][cc] = __builtin_amdgcn_mfma_f32_16x16x32_bf16(af0, bfr, acc[0][cc], 0, 0, 0);
            acc[1][cc] = __builtin_amdgcn_mfma_f32_16x16x32_bf16(af1, bfr, acc[1][cc], 0, 0, 0);
        }
    }
    // C/D layout (verified m89): col = lane&15, row = (lane>>4)*4 + reg
#pragma unroll
    for (int r = 0; r < 2; ++r) {
#pragma unroll
        for (int cc = 0; cc < 8; ++cc) {
            const int col = (colhalf << 7) + cc * 16 + lr;
#pragma unroll
            for (int reg = 0; reg < 4; ++reg) {
                const long row = rowbase + r * 16 + lk * 4 + reg;
                const float v = acc[r][cc][reg];
                if constexpr (sizeof(OutT) == 2) C[row * HID + col] = __float2bfloat16(v);
                else                             C[row * HID + col] = v;
            }
        }
    }
}

// ---------------- alpha = softmax_d(q*w_alpha*scale); gq = segment_sum(alpha*q) ----------------
__global__ __launch_bounds__(256) void alpha_gq_kernel(const bf16* __restrict__ qb,
                                                       const float* __restrict__ w_alpha,
                                                       const int* __restrict__ seg,
                                                       float* __restrict__ gq) {
    const int j = threadIdx.x;
    const float wa = w_alpha[j & 31] * SMSCALE;
    const long n0 = (long)blockIdx.x * CHUNK;
    float acc = 0.f;
    int cur = -1;
    for (int i = 0; i < CHUNK; ++i) {
        const long n = n0 + i;
        const int s = seg[n];
        const float qv = bf2f(qb[n * HID + j]);
        const float x = qv * wa;
        const float m = gmax32(x);
        const float e = __expf(x - m);
        const float ssum = gsum32(e);
        const float alpha = e / ssum;
        if (s != cur) {
            if (cur >= 0) atomicAdd(&gq[(long)cur * HID + j], acc);
            acc = 0.f;
            cur = s;
        }
        acc += alpha * qv;
    }
    atomicAdd(&gq[(long)cur * HID + j], acc);
}

// ---------------- p = gq[seg]*k; beta = softmax_d(p*w_beta*scale); gk = segment_sum(beta*p) ----
__global__ __launch_bounds__(256) void beta_gk_kernel(const bf16* __restrict__ kb,
                                                      const float* __restrict__ gq,
                                                      const float* __restrict__ w_beta,
                                                      const int* __restrict__ seg,
                                                      float* __restrict__ gk) {
    const int j = threadIdx.x;
    const float wb = w_beta[j & 31] * SMSCALE;
    const long n0 = (long)blockIdx.x * CHUNK;
    float acc = 0.f;
    int cur = -1;
    for (int i = 0; i < CHUNK; ++i) {
        const long n = n0 + i;
        const int s = seg[n];
        const float kv = bf2f(kb[n * HID + j]);
        const float p = gq[(long)s * HID + j] * kv;
        const float x = p * wb;
        const float m = gmax32(x);
        const float e = __expf(x - m);
        const float ssum = gsum32(e);
        const float beta = e / ssum;
        if (s != cur) {
            if (cur >= 0) atomicAdd(&gk[(long)cur * HID + j], acc);
            acc = 0.f;
            cur = s;
        }
        acc += beta * p;
    }
    atomicAdd(&gk[(long)cur * HID + j], acc);
}

// ---------------- act = relu((gk[seg]*v) @ W_r^T per head + q), EXACT f32 ------------------
// One thread per (bond, head). Wr (32x32 f32, 4 KB) staged in LDS; per-step all lanes read
// the same address -> broadcast, conflict-free. kvi[32] in registers; 1024 fully-unrolled
// f32 fma. Numerically identical to R1's passing act (f32 throughout, same sum order),
// without R1's 2048 serial __shfl chain (305 us @ 8% BW).
__global__ __launch_bounds__(256) void act_exact_kernel(const ushort* __restrict__ vb,
                                                        const ushort* __restrict__ qb,
                                                        const float* __restrict__ gk,
                                                        const float* __restrict__ Wr,
                                                        const int* __restrict__ seg,
                                                        ushort* __restrict__ act) {
    __shared__ __align__(16) float wr_lds[1024];
    const int t = threadIdx.x;
#pragma unroll
    for (int i = 0; i < 4; ++i) wr_lds[i * 256 + t] = Wr[i * 256 + t];
    __syncthreads();

    const long tid = (long)blockIdx.x * 256 + t;  // flat (n, h) row index
    const int n = (int)(tid >> 3), h = (int)(tid & 7);
    const int sid = seg[n];

    const float* gp = gk + (long)sid * HID + h * 32;
    const ushort* vp = vb + tid * 32;
    float kvi[32];
#pragma unroll
    for (int dq = 0; dq < 4; ++dq) {
        short8_t v8 = *reinterpret_cast<const short8_t*>(vp + dq * 8);
        float4 ga = reinterpret_cast<const float4*>(gp)[dq * 2];
        float4 gb = reinterpret_cast<const float4*>(gp)[dq * 2 + 1];
        kvi[dq * 8 + 0] = ga.x * us2f((ushort)v8[0]);
        kvi[dq * 8 + 1] = ga.y * us2f((ushort)v8[1]);
        kvi[dq * 8 + 2] = ga.z * us2f((ushort)v8[2]);
        kvi[dq * 8 + 3] = ga.w * us2f((ushort)v8[3]);
        kvi[dq * 8 + 4] = gb.x * us2f((ushort)v8[4]);
        kvi[dq * 8 + 5] = gb.y * us2f((ushort)v8[5]);
        kvi[dq * 8 + 6] = gb.z * us2f((ushort)v8[6]);
        kvi[dq * 8 + 7] = gb.w * us2f((ushort)v8[7]);
    }

    const ushort* qp = qb + tid * 32;
    short8_t q8[4];
#pragma unroll
    for (int i = 0; i < 4; ++i) q8[i] = *reinterpret_cast<const short8_t*>(qp + i * 8);

    short8_t ob[4];
#pragma unroll
    for (int e = 0; e < 32; ++e) {
        float acc = 0.f;
        const float4* wre = reinterpret_cast<const float4*>(wr_lds + e * 32);
#pragma unroll
        for (int dq = 0; dq < 8; ++dq) {
            float4 w = wre[dq];
            acc = fmaf(kvi[dq * 4 + 0], w.x, acc);
            acc = fmaf(kvi[dq * 4 + 1], w.y, acc);
            acc = fmaf(kvi[dq * 4 + 2], w.z, acc);
            acc = fmaf(kvi[dq * 4 + 3], w.w, acc);
        }
        const float qv = us2f((ushort)q8[e >> 3][e & 7]);
        ob[e >> 3][e & 7] = f2bs(fmaxf(acc + qv, 0.f));
    }

    ushort* ap = act + tid * 32;
#pragma unroll
    for (int i = 0; i < 4; ++i) *reinterpret_cast<short8_t*>(ap + i * 8) = ob[i];
}

// ---------------- LayerNorm: one wave per row (4 f32 per lane), write d_out row n+1 ----------
// VERBATIM from R1 (known-pass).
__global__ __launch_bounds__(256) void ln_kernel(const float* __restrict__ tmp,
                                                 const float* __restrict__ b_o,
                                                 const float* __restrict__ gamma,
                                                 const float* __restrict__ beta_ln,
                                                 float* __restrict__ out) {
    const int wave = threadIdx.x >> 6, lane = threadIdx.x & 63;
    const long row = (long)blockIdx.x * 4 + wave;
    const float4 bo = reinterpret_cast<const float4*>(b_o)[lane];
    const float4 g = reinterpret_cast<const float4*>(gamma)[lane];
    const float4 bl = reinterpret_cast<const float4*>(beta_ln)[lane];
    float4 x = reinterpret_cast<const float4*>(tmp + row * HID)[lane];
    x.x += bo.x; x.y += bo.y; x.z += bo.z; x.w += bo.w;
    float s = x.x + x.y + x.z + x.w;
#pragma unroll
    for (int m = 32; m >= 1; m >>= 1) s += __shfl_xor(s, m);
    const float mu = s * (1.f / HID);
    float4 dx = {x.x - mu, x.y - mu, x.z - mu, x.w - mu};
    float sq = dx.x * dx.x + dx.y * dx.y + dx.z * dx.z + dx.w * dx.w;
#pragma unroll
    for (int m = 32; m >= 1; m >>= 1) sq += __shfl_xor(sq, m);
    const float r = rsqrtf(sq * (1.f / HID) + LN_EPS);
    float4 o;
    o.x = dx.x * r * g.x + bl.x;
    o.y = dx.y * r * g.y + bl.y;
    o.z = dx.z * r * g.z + bl.z;
    o.w = dx.w * r * g.w + bl.w;
    reinterpret_cast<float4*>(out + (row + 1) * HID)[lane] = o;
}

extern "C" void kernel_launch(void* const* d_in, const int* in_sizes, int n_in,
                              void* d_out, int out_size, void* d_ws, size_t ws_size,
                              hipStream_t stream) {
    const float* msg    = (const float*)d_in[0];
    const float* Wq     = (const float*)d_in[1];
    const float* Wk     = (const float*)d_in[2];
    const float* Wv     = (const float*)d_in[3];
    const float* Wr     = (const float*)d_in[4];
    const float* walpha = (const float*)d_in[5];
    const float* wbeta  = (const float*)d_in[6];
    const float* Wo     = (const float*)d_in[7];
    const float* bo     = (const float*)d_in[8];
    const float* gamma  = (const float*)d_in[9];
    const float* betaln = (const float*)d_in[10];
    const int*   seg    = (const int*)d_in[11];

    // workspace layout (R1-identical): msgb | qb | kb | vb | wqb wkb wvb wob | gq gk
    // act (bf16) reuses msgb; tmp (f32, N*H) reuses qb+kb (dead after act).
    char* ws = (char*)d_ws;
    const size_t nh = (size_t)N_BONDS * HID;
    size_t off = 0;
    bf16* msgb = (bf16*)(ws + off); off += nh * 2;
    bf16* qb   = (bf16*)(ws + off); off += nh * 2;
    bf16* kb   = (bf16*)(ws + off); off += nh * 2;
    bf16* vb   = (bf16*)(ws + off); off += nh * 2;
    bf16* wqb  = (bf16*)(ws + off); off += (size_t)HID * HID * 2;
    bf16* wkb  = (bf16*)(ws + off); off += (size_t)HID * HID * 2;
    bf16* wvb  = (bf16*)(ws + off); off += (size_t)HID * HID * 2;
    bf16* wob  = (bf16*)(ws + off); off += (size_t)HID * HID * 2;
    float* gq  = (float*)(ws + off); off += (size_t)NSEG * HID * 4;
    float* gk  = (float*)(ws + off); off += (size_t)NSEG * HID * 4;
    bf16*  act = msgb;
    float* tmp = (float*)qb;

    hipMemsetAsync(gq, 0, (size_t)2 * NSEG * HID * 4, stream);
    hipMemsetAsync(d_out, 0, HID * sizeof(float), stream);

    cast_kernel<<<4096, 256, 0, stream>>>(msg, (ushort*)msgb, (int)(nh / 4));
    cast_kernel<<<64, 256, 0, stream>>>(Wq, (ushort*)wqb, HID * HID / 4);
    cast_kernel<<<64, 256, 0, stream>>>(Wk, (ushort*)wkb, HID * HID / 4);
    cast_kernel<<<64, 256, 0, stream>>>(Wv, (ushort*)wvb, HID * HID / 4);
    cast_kernel<<<64, 256, 0, stream>>>(Wo, (ushort*)wob, HID * HID / 4);

    dim3 gg(N_BONDS / 128, 2);
    gemm_bt<bf16><<<gg, 256, 0, stream>>>((const ushort*)msgb, (const ushort*)wqb, qb);
    gemm_bt<bf16><<<gg, 256, 0, stream>>>((const ushort*)msgb, (const ushort*)wkb, kb);
    gemm_bt<bf16><<<gg, 256, 0, stream>>>((const ushort*)msgb, (const ushort*)wvb, vb);

    alpha_gq_kernel<<<N_BONDS / CHUNK, 256, 0, stream>>>(qb, walpha, seg, gq);
    beta_gk_kernel<<<N_BONDS / CHUNK, 256, 0, stream>>>(kb, gq, wbeta, seg, gk);

    act_exact_kernel<<<N_BONDS * 8 / 256, 256, 0, stream>>>((const ushort*)vb, (const ushort*)qb,
                                                            gk, Wr, seg, (ushort*)act);

    gemm_bt<float><<<gg, 256, 0, stream>>>((const ushort*)act, (const ushort*)wob, tmp);
    ln_kernel<<<N_BONDS / 4, 256, 0, stream>>>(tmp, bo, gamma, betaln, (float*)d_out);
}